// Round 3
// baseline (993.650 us; speedup 1.0000x reference)
//
#include <hip/hip_runtime.h>
#include <math.h>

#define TOKENS  16384
#define HIDDEN  4096
#define NEXPERT 256
#define NGROUP  8
#define GSIZE   32
#define TOPKG   4
#define TOPK    8
#define RSCALE  2.5f

// One fused kernel: block = 64 tokens x ALL 256 experts, full K, routing in
// epilogue. Round-6 change: A-fragments move from LDS to the SCALAR path.
// Round-5 counters showed LDS-BW-bound: 1.5 B/FMA demand (2 b128 A-broadcast
// + 1 b128 B per 32 FMA) = 493 us of LDS cycles at 85 B/cy/CU ~= measured
// 537 us, with VALUBusy stuck at 56%. The A broadcast moves 1 KiB/instr to
// deliver 16 unique bytes (64x redundancy). A-frag rows are wave-uniform ->
// load via uniform address (readfirstlane'd wave id) so the compiler selects
// s_load_dwordx4 into SGPRs; v_fmac takes the SGPR operand directly. LDS now
// carries only B: 0.5 B/FMA = 164 us < 218 us VALU floor -> VALU-bound.
// fp32 ascending-k fmaf chain per logit is BIT-IDENTICAL (same float values,
// same order); routing untouched.
#define BM   64
#define BK   16
#define LDB  260   // B-tile leading pad
#define NTHR 512

__device__ __forceinline__ float sigmoid_acc(float x) {
    return 1.0f / (1.0f + expf(-x));   // accurate expf: top-k order must match ref
}

__global__ __launch_bounds__(NTHR, 2) __attribute__((amdgpu_waves_per_eu(2, 2)))
void moe_gate_fused(const float* __restrict__ A,      // [TOKENS, HIDDEN]
                    const float* __restrict__ B,      // [NEXPERT, HIDDEN]
                    const float* __restrict__ bias,   // [NEXPERT]
                    float* __restrict__ out_idx,
                    float* __restrict__ out_w,
                    float* __restrict__ out_logits)
{
    __shared__ float Bs[2][BK * LDB];          // Bs[k][n], 256 rows
    __shared__ float gsum[BM][NGROUP + 1];

    const int tid = threadIdx.x;
    const int m0  = blockIdx.x * BM;

    // ---- B staging map (512 threads) ----
    // B: 256x16 tile = 1024 float4 -> 2 float4/thread (8 contiguous floats
    //    of one row; 2 lanes cover 64B of a row).
    const int ar_b = tid >> 1;          // 0..255 B row
    const int q0   = (tid & 1) * 2;     // k-quad pair {0,1} or {2,3}
    const float* Bg = B + (long)ar_b * HIDDEN + q0 * 4;

    // ---- compute map: 8 waves x 64 lanes, 8x4 micro-tile ----
    // Wave w owns token rows w*8..w*8+7 (wave-uniform -> A via scalar loads).
    // Lane tc owns expert cols tc*4..tc*4+3 (contiguous 1KiB b128 line,
    // conflict-free).
    const int w8   = __builtin_amdgcn_readfirstlane(tid >> 6);   // wave 0..7
    const int tc   = tid & 63;
    const int row0 = w8 * 8;
    const int c0   = tc * 4;

    const float* Aw = A + (long)(m0 + row0) * HIDDEN;   // wave-uniform base

    float4 pb0, pb1;

    // prefetch + stage tile 0 -> buffer 0
    pb0 = *(const float4*)(Bg);
    pb1 = *(const float4*)(Bg + 4);
    {
        float* bs = Bs[0];
        bs[(q0 * 4 + 0) * LDB + ar_b] = pb0.x;
        bs[(q0 * 4 + 1) * LDB + ar_b] = pb0.y;
        bs[(q0 * 4 + 2) * LDB + ar_b] = pb0.z;
        bs[(q0 * 4 + 3) * LDB + ar_b] = pb0.w;
        bs[(q0 * 4 + 4) * LDB + ar_b] = pb1.x;
        bs[(q0 * 4 + 5) * LDB + ar_b] = pb1.y;
        bs[(q0 * 4 + 6) * LDB + ar_b] = pb1.z;
        bs[(q0 * 4 + 7) * LDB + ar_b] = pb1.w;
    }
    __syncthreads();

    float acc[8][4] = {};

    const int NKT = HIDDEN / BK;   // 256
    for (int kt = 0; kt < NKT; ++kt) {
        const int cur = kt & 1;

        if (kt + 1 < NKT) {
            const int ko = (kt + 1) * BK;
            pb0 = *(const float4*)(Bg + ko);
            pb1 = *(const float4*)(Bg + ko + 4);
        }

        const float* bs = Bs[cur];
        const int kb = kt * BK;
        #pragma unroll
        for (int q = 0; q < 4; ++q) {
            // A quads for this k-group: uniform address -> s_load_dwordx4.
            // One 64B scalar-cache line per row per kt.
            float4 aq[8];
            #pragma unroll
            for (int i = 0; i < 8; ++i)
                aq[i] = *(const float4*)(Aw + i * HIDDEN + kb + q * 4);
            #pragma unroll
            for (int kk = 0; kk < 4; ++kk) {
                const int k = q * 4 + kk;
                float4 b0 = *(const float4*)(bs + k * LDB + c0);  // conflict-free
                #pragma unroll
                for (int i = 0; i < 8; ++i) {
                    float a = (kk == 0) ? aq[i].x : (kk == 1) ? aq[i].y
                            : (kk == 2) ? aq[i].z : aq[i].w;
                    acc[i][0] = fmaf(a, b0.x, acc[i][0]);
                    acc[i][1] = fmaf(a, b0.y, acc[i][1]);
                    acc[i][2] = fmaf(a, b0.z, acc[i][2]);
                    acc[i][3] = fmaf(a, b0.w, acc[i][3]);
                }
            }
        }

        if (kt + 1 < NKT) {
            float* bs_w = Bs[cur ^ 1];
            bs_w[(q0 * 4 + 0) * LDB + ar_b] = pb0.x;
            bs_w[(q0 * 4 + 1) * LDB + ar_b] = pb0.y;
            bs_w[(q0 * 4 + 2) * LDB + ar_b] = pb0.z;
            bs_w[(q0 * 4 + 3) * LDB + ar_b] = pb0.w;
            bs_w[(q0 * 4 + 4) * LDB + ar_b] = pb1.x;
            bs_w[(q0 * 4 + 5) * LDB + ar_b] = pb1.y;
            bs_w[(q0 * 4 + 6) * LDB + ar_b] = pb1.z;
            bs_w[(q0 * 4 + 7) * LDB + ar_b] = pb1.w;
        }
        __syncthreads();
    }

    // ---- epilogue: write logits (coalesced float4) ----
    #pragma unroll
    for (int i = 0; i < 8; ++i) {
        long row = m0 + row0 + i;
        *(float4*)(out_logits + row * NEXPERT + c0) =
            make_float4(acc[i][0], acc[i][1], acc[i][2], acc[i][3]);
    }
    __syncthreads();   // barrier drains vmcnt -> this block's logits visible via its L2

    // ---- routing phase A: per (token, group) top-2 of sigmoid(logit)+bias ----
    for (int task = tid; task < BM * NGROUP; task += NTHR) {
        const int tt = task >> 3;
        const int g  = task & 7;
        const float* lg = out_logits + (long)(m0 + tt) * NEXPERT + g * GSIZE;
        const float* bp = bias + g * GSIZE;
        float m1 = -INFINITY, m2 = -INFINITY;
        #pragma unroll
        for (int j4 = 0; j4 < GSIZE / 4; ++j4) {
            float4 l = *(const float4*)(lg + j4 * 4);
            float4 b = *(const float4*)(bp + j4 * 4);
            float vv[4] = {sigmoid_acc(l.x) + b.x, sigmoid_acc(l.y) + b.y,
                           sigmoid_acc(l.z) + b.z, sigmoid_acc(l.w) + b.w};
            #pragma unroll
            for (int c = 0; c < 4; ++c) {
                float x = vv[c];
                if (x > m1) { m2 = m1; m1 = x; }
                else if (x > m2) { m2 = x; }
            }
        }
        gsum[tt][g] = m1 + m2;
    }
    __syncthreads();

    // ---- routing phase B: one worker per token ----
    if (tid < BM) {
        const long tok = m0 + tid;
        const float* lg = out_logits + tok * NEXPERT;

        float gs[NGROUP];
        #pragma unroll
        for (int g = 0; g < NGROUP; ++g) gs[g] = gsum[tid][g];

        unsigned selmask = 0;
        #pragma unroll
        for (int r = 0; r < TOPKG; ++r) {
            float best = -INFINITY; int bi = 0;
            #pragma unroll
            for (int g = 0; g < NGROUP; ++g) {
                bool taken = (selmask >> g) & 1u;
                if (!taken && gs[g] > best) { best = gs[g]; bi = g; }
            }
            selmask |= 1u << bi;
        }

        float rv[TOPK]; int ri[TOPK];
        #pragma unroll
        for (int k = 0; k < TOPK; ++k) { rv[k] = -INFINITY; ri[k] = 0; }

        for (int g = 0; g < NGROUP; ++g) {
            if (!((selmask >> g) & 1u)) continue;
            #pragma unroll 4
            for (int j = 0; j < GSIZE; ++j) {
                int e = g * GSIZE + j;
                float v = sigmoid_acc(lg[e]) + bias[e];
                if (v > rv[TOPK - 1]) {
                    rv[TOPK - 1] = v; ri[TOPK - 1] = e;
                    #pragma unroll
                    for (int q = TOPK - 1; q > 0; --q) {
                        if (rv[q] > rv[q - 1]) {
                            float tv = rv[q]; rv[q] = rv[q - 1]; rv[q - 1] = tv;
                            int   ti = ri[q]; ri[q] = ri[q - 1]; ri[q - 1] = ti;
                        }
                    }
                }
            }
        }

        float pv[TOPK]; float sum = 0.0f;
        #pragma unroll
        for (int k = 0; k < TOPK; ++k) { pv[k] = rv[k] - bias[ri[k]]; sum += pv[k]; }
        float denom = sum + 1e-20f;

        #pragma unroll
        for (int k = 0; k < TOPK; ++k) {
            out_idx[tok * TOPK + k] = (float)ri[k];
            out_w[tok * TOPK + k]   = pv[k] / denom * RSCALE;
        }
    }
}

// ---------------- launch ----------------
extern "C" void kernel_launch(void* const* d_in, const int* in_sizes, int n_in,
                              void* d_out, int out_size, void* d_ws, size_t ws_size,
                              hipStream_t stream) {
    const float* hidden = (const float*)d_in[0];
    const float* gate_w = (const float*)d_in[1];
    const float* bias   = (const float*)d_in[2];

    float* out = (float*)d_out;
    float* out_idx    = out;
    float* out_w      = out + (long)TOKENS * TOPK;
    float* out_logits = out + (long)TOKENS * TOPK * 2;

    moe_gate_fused<<<TOKENS / BM, NTHR, 0, stream>>>(
        hidden, gate_w, bias, out_idx, out_w, out_logits);
}